// Round 5
// baseline (133.596 us; speedup 1.0000x reference)
//
#include <hip/hip_runtime.h>

#define Bn 256
#define Tn 256
#define Hn 16
#define Dn 88
#define LOG16 2.7725887222397811f

// ---------------------------------------------------------------------------
// DPP helpers: row_ror rotations within 16-lane rows; self-calibrated usage.
// ---------------------------------------------------------------------------
template<int CTRL>
__device__ __forceinline__ float dppf(float x) {
    return __int_as_float(__builtin_amdgcn_update_dpp(
        0, __float_as_int(x), CTRL, 0xF, 0xF, true));
}
#define GATHER16(dst, s)                                                     \
    dst[0] = (s);                                                            \
    dst[1] = dppf<0x128>(dst[0]);                                            \
    dst[2] = dppf<0x124>(dst[0]); dst[3]  = dppf<0x124>(dst[1]);             \
    dst[4] = dppf<0x122>(dst[0]); dst[5]  = dppf<0x122>(dst[1]);             \
    dst[6] = dppf<0x122>(dst[2]); dst[7]  = dppf<0x122>(dst[3]);             \
    dst[8] = dppf<0x121>(dst[0]); dst[9]  = dppf<0x121>(dst[1]);             \
    dst[10] = dppf<0x121>(dst[2]); dst[11] = dppf<0x121>(dst[3]);            \
    dst[12] = dppf<0x121>(dst[4]); dst[13] = dppf<0x121>(dst[5]);            \
    dst[14] = dppf<0x121>(dst[6]); dst[15] = dppf<0x121>(dst[7]);

__device__ __forceinline__ float rowsum16(float v) {
    v += dppf<0x128>(v); v += dppf<0x124>(v);
    v += dppf<0x122>(v); v += dppf<0x121>(v);
    return v;
}

// ---------------------------------------------------------------------------
// One block per sequence b; 256 threads; producer/consumer wave pipeline.
//   waves 1-3 (producers): build LUT + nibble-pack seq, then emit Esh in
//     16-t granules (round-robin), publishing each granule with a release
//     store to flags[g]. They also pre-reduce the masked max-shift sum into
//     msumAcc (one LDS atomic per granule).
//   wave 0 (consumer): runs the serial scaled linear-space forward recursion,
//     acquire-spinning on flags only at granule boundaries (it runs slower
//     than the producers, so spinning ~ vanishes after granule 0).
// ---------------------------------------------------------------------------
__global__ __launch_bounds__(256) void fused_kernel(
    const float* __restrict__ seq,
    const int*   __restrict__ lengths,
    const float* __restrict__ probs_x,
    const float* __restrict__ probs_y,
    float* __restrict__ out)
{
    __shared__ __align__(16) float lut[Dn * 64];   // 22528 B  [d][pc][h]
    __shared__ unsigned nibW[Tn * 6];              //  6144 B  4 bits/elem
    __shared__ __align__(16) float Esh[Tn * Hn];   // 16384 B
    __shared__ int flags[16];                      // granule-ready flags
    __shared__ float msumAcc;                      // sum of masked max-shifts

    const int tid = threadIdx.x;
    const int b = blockIdx.x;
    int len = lengths[b];
    len = min(max(len, 0), Tn);

    if (tid < 64) {
        if (tid < 16) flags[tid] = 0;
        if (tid == 16) msumAcc = 0.0f;
    } else {
        const int ptid = tid - 64;                 // 0..191
        // ---- LUT (linear writes: conflict-free; scattered 4B reads ok) ----
        for (int i = ptid; i < Dn * 64; i += 192) {
            int h = i & 15, pc = (i >> 4) & 3, d = i >> 6;
            float p = probs_y[(h * 2 + (pc >> 1)) * Dn + d];
            lut[i] = (pc & 1) ? __logf(p) : __logf(1.0f - p);
        }
        // ---- nibble-pack seq[b] ----
        for (int t = ptid; t < Tn; t += 192)
            ((unsigned short*)nibW)[t * 12 + 11] = 0;   // zero pad bytes 22..23
        const float4* seqv = (const float4*)(seq + (size_t)b * Tn * Dn);
        #pragma unroll
        for (int k = 0; k < 30; ++k) {
            int f = ptid + k * 192;                     // flat float4 index
            if (f < (Tn * Dn) / 4) {
                float4 v = seqv[f];
                int t = f / 22, jj = f - t * 22;
                unsigned nib = (v.x > 0.5f ? 1u : 0u) | (v.y > 0.5f ? 2u : 0u) |
                               (v.z > 0.5f ? 4u : 0u) | (v.w > 0.5f ? 8u : 0u);
                ((unsigned char*)nibW)[t * 24 + jj] = (unsigned char)nib;
            }
        }
    }
    __syncthreads();

    if (tid >= 64) {
        // =================== producers: waves 1..3 ===================
        const int wv = tid >> 6;            // 1..3
        const int lane = tid & 63;
        const int tloc = lane >> 2, h4i = lane & 3;
        const float4* lv = (const float4*)lut;

        for (int g = wv - 1; g < 16; g += 3) {
            const int t = (g << 4) + tloc;
            unsigned cw0, cw1, cw2, pw0, pw1, pw2;
            {
                unsigned n0 = nibW[t * 6 + 0], n1 = nibW[t * 6 + 1], n2 = nibW[t * 6 + 2];
                unsigned n3 = nibW[t * 6 + 3], n4 = nibW[t * 6 + 4], n5 = nibW[t * 6 + 5];
                auto c4 = [](unsigned w) { unsigned y = (w | (w >> 4)) & 0x00FF00FFu;
                                           return (y | (y >> 8)) & 0xFFFFu; };
                cw0 = c4(n0) | (c4(n1) << 16);
                cw1 = c4(n2) | (c4(n3) << 16);
                cw2 = c4(n4) | (c4(n5) << 16);
            }
            if (t > 0) {
                unsigned n0 = nibW[t * 6 - 6], n1 = nibW[t * 6 - 5], n2 = nibW[t * 6 - 4];
                unsigned n3 = nibW[t * 6 - 3], n4 = nibW[t * 6 - 2], n5 = nibW[t * 6 - 1];
                auto c4 = [](unsigned w) { unsigned y = (w | (w >> 4)) & 0x00FF00FFu;
                                           return (y | (y >> 8)) & 0xFFFFu; };
                pw0 = c4(n0) | (c4(n1) << 16);
                pw1 = c4(n2) | (c4(n3) << 16);
                pw2 = c4(n4) | (c4(n5) << 16);
            } else { pw0 = pw1 = pw2 = 0; }

            float4 acc = {0.f, 0.f, 0.f, 0.f};
            #pragma unroll 8
            for (int d = 0; d < 32; ++d) {
                int idx = (d << 4) + (((pw0 >> d) & 1u) << 3) + (((cw0 >> d) & 1u) << 2) + h4i;
                float4 v = lv[idx];
                acc.x += v.x; acc.y += v.y; acc.z += v.z; acc.w += v.w;
            }
            #pragma unroll 8
            for (int d = 0; d < 32; ++d) {
                int idx = ((d + 32) << 4) + (((pw1 >> d) & 1u) << 3) + (((cw1 >> d) & 1u) << 2) + h4i;
                float4 v = lv[idx];
                acc.x += v.x; acc.y += v.y; acc.z += v.z; acc.w += v.w;
            }
            #pragma unroll 8
            for (int d = 0; d < 24; ++d) {
                int idx = ((d + 64) << 4) + (((pw2 >> d) & 1u) << 3) + (((cw2 >> d) & 1u) << 2) + h4i;
                float4 v = lv[idx];
                acc.x += v.x; acc.y += v.y; acc.z += v.z; acc.w += v.w;
            }

            float mx = fmaxf(fmaxf(acc.x, acc.y), fmaxf(acc.z, acc.w));
            mx = fmaxf(mx, __shfl_xor(mx, 1, 4));
            mx = fmaxf(mx, __shfl_xor(mx, 2, 4));
            float4 E;
            E.x = __expf(acc.x - mx); E.y = __expf(acc.y - mx);
            E.z = __expf(acc.z - mx); E.w = __expf(acc.w - mx);
            ((float4*)Esh)[(t << 2) + h4i] = E;

            // masked max-shift partial sum for this granule (16 t's)
            float val = (h4i == 0 && t < len) ? mx : 0.0f;
            val += __shfl_xor(val, 4);
            val += __shfl_xor(val, 8);
            val += __shfl_xor(val, 16);
            val += __shfl_xor(val, 32);
            if (lane == 0) {
                atomicAdd(&msumAcc, val);
                __hip_atomic_store(&flags[g], 1, __ATOMIC_RELEASE,
                                   __HIP_MEMORY_SCOPE_WORKGROUP);
            }
        }
        return;
    }

    // =================== consumer: wave 0 ===================
    const int j = tid & 15;

    float cal[16];
    GATHER16(cal, (float)j);                    // learn the network's permutation
    float pcr[16];
    #pragma unroll
    for (int k = 0; k < 16; ++k) pcr[k] = probs_x[((int)cal[k]) * Hn + j];

    while (__hip_atomic_load(&flags[0], __ATOMIC_ACQUIRE,
                             __HIP_MEMORY_SCOPE_WORKGROUP) == 0) {}

    float a = (j == 0) ? 1.0f : 0.0f;           // alpha0 one-hot, linear space
    float L = 0.0f;
    float eb[8];
    #pragma unroll
    for (int k = 0; k < 8; ++k) eb[k] = Esh[(k << 4) + j];

    for (int t = 0; t < len; ++t) {
        if ((t & 15) == 8 && t + 8 < Tn) {      // next granule needed by prefetch
            const int g = (t + 8) >> 4;
            while (__hip_atomic_load(&flags[g], __ATOMIC_ACQUIRE,
                                     __HIP_MEMORY_SCOPE_WORKGROUP) == 0) {}
        }
        float e = eb[t & 7];
        int tn = t + 8; tn = (tn < Tn) ? tn : (Tn - 1);
        eb[t & 7] = Esh[(tn << 4) + j];

        float y[16];
        GATHER16(y, a);
        float s0 = y[0] * pcr[0], s1 = y[1] * pcr[1];
        float s2 = y[2] * pcr[2], s3 = y[3] * pcr[3];
        #pragma unroll
        for (int k = 4; k < 16; k += 4) {
            s0 = fmaf(y[k + 0], pcr[k + 0], s0);
            s1 = fmaf(y[k + 1], pcr[k + 1], s1);
            s2 = fmaf(y[k + 2], pcr[k + 2], s2);
            s3 = fmaf(y[k + 3], pcr[k + 3], s3);
        }
        a = ((s0 + s1) + (s2 + s3)) * e;

        if ((t & 7) == 7) {                     // renorm (identity on L+log S)
            float S = rowsum16(a);
            a *= (1.0f / S);
            L += __logf(S);
        }
    }

    // make sure every producer granule (and its msumAcc add) has landed
    #pragma unroll
    for (int g = 0; g < 16; ++g)
        while (__hip_atomic_load(&flags[g], __ATOMIC_ACQUIRE,
                                 __HIP_MEMORY_SCOPE_WORKGROUP) == 0) {}
    L += msumAcc;

    float S = rowsum16(a);
    float res = L + __logf(S) + (float)(Tn - len) * LOG16;
    if (tid == 0) atomicAdd(out, res);
}

extern "C" void kernel_launch(void* const* d_in, const int* in_sizes, int n_in,
                              void* d_out, int out_size, void* d_ws, size_t ws_size,
                              hipStream_t stream) {
    const float* seq     = (const float*)d_in[0];
    const int*   lengths = (const int*)  d_in[1];
    const float* probs_x = (const float*)d_in[2];
    const float* probs_y = (const float*)d_in[3];
    float* out = (float*)d_out;

    hipMemsetAsync(d_out, 0, sizeof(float) * out_size, stream);
    fused_kernel<<<Bn, 256, 0, stream>>>(seq, lengths, probs_x, probs_y, out);
}